// Round 12
// baseline (200.392 us; speedup 1.0000x reference)
//
#include <hip/hip_runtime.h>
#include <math.h>

typedef __attribute__((ext_vector_type(8))) short    short8;
typedef __attribute__((ext_vector_type(4))) float    f32x4;
typedef __attribute__((ext_vector_type(4))) unsigned uint4v;

#define FRAG0 256   // u32 offset of frag region in ws

__device__ __forceinline__ unsigned short f2bf(float f) {   // RNE
    unsigned u = __builtin_bit_cast(unsigned, f);
    u = u + 0x7fffu + ((u >> 16) & 1u);
    return (unsigned short)(u >> 16);
}
__device__ __forceinline__ unsigned packRNE(float hi, float lo) {
    return (unsigned)f2bf(lo) | ((unsigned)f2bf(hi) << 16);
}
__device__ __forceinline__ unsigned pack_trunc(float hi, float lo) {  // 1 v_perm
    return __builtin_amdgcn_perm(__builtin_bit_cast(unsigned, hi),
                                 __builtin_bit_cast(unsigned, lo), 0x07060302u);
}
__device__ __forceinline__ float rfl(float x) {
    return __builtin_bit_cast(float, __builtin_amdgcn_readfirstlane(__builtin_bit_cast(int, x)));
}
__device__ __forceinline__ f32x4 mfma16(short8 a, short8 b, f32x4 c) {
    return __builtin_amdgcn_mfma_f32_16x16x32_bf16(a, b, c, 0, 0, 0);
}
__device__ __forceinline__ unsigned bperm(int addr, unsigned v) {
    return (unsigned)__builtin_amdgcn_ds_bpermute(addr, (int)v);
}
template<int PAT>
__device__ __forceinline__ float swzXf(float v) {
    return __builtin_bit_cast(float, __builtin_amdgcn_ds_swizzle(__builtin_bit_cast(int, v), PAT));
}
__device__ __forceinline__ float sigf(float x) { return __builtin_amdgcn_rcpf(1.f + __expf(-x)); }
__device__ __forceinline__ float tanhfast(float x) {
    float e = __expf(2.f * x);
    return 1.f - 2.f * __builtin_amdgcn_rcpf(e + 1.f);
}
__device__ __forceinline__ f32x4 ld4(const float* p) { return *(const f32x4*)p; }

__device__ __forceinline__ void packC(unsigned* P, f32x4 a0, f32x4 a1, bool oob) {
    float r0 = fmaxf(a0[0], 0.f), r1 = fmaxf(a0[1], 0.f), r2 = fmaxf(a0[2], 0.f), r3 = fmaxf(a0[3], 0.f);
    float s0 = fmaxf(a1[0], 0.f), s1 = fmaxf(a1[1], 0.f), s2 = fmaxf(a1[2], 0.f), s3 = fmaxf(a1[3], 0.f);
    P[0] = pack_trunc(r1, r0); P[1] = pack_trunc(r3, r2);
    P[2] = pack_trunc(s1, s0); P[3] = pack_trunc(s3, s2);
    if (oob) { P[0] = 0u; P[1] = 0u; P[2] = 0u; P[3] = 0u; }
}

// ===================== prep kernel (verbatim R10) =====================
__global__ __launch_bounds__(256) void r2p2_prep(
    const float* __restrict__ w0, const float* __restrict__ w1,
    const float* __restrict__ w2, const float* __restrict__ w3,
    const float* __restrict__ enc_whh,
    const float* __restrict__ dec_wih, const float* __restrict__ dec_whh,
    const float* __restrict__ mw1, const float* __restrict__ mb1,
    const float* __restrict__ mw2, const float* __restrict__ mb2,
    float* __restrict__ wsf, unsigned* __restrict__ wsu) {
    const int tid = threadIdx.x, bx = blockIdx.x;
    __shared__ __align__(16) short s[4224];
    __shared__ float red[64];

    if (bx == 0) {
        if (tid < 128) {
            int k = tid & 31, j = tid >> 5;
            const float* w2r = mw2 + j * 512;
            float a0 = 0.f, a1 = 0.f, a2 = 0.f, a3 = 0.f;
#pragma unroll 4
            for (int m = 0; m < 512; m += 4) {
                a0 = fmaf(w2r[m],     mw1[m * 32 + k],       a0);
                a1 = fmaf(w2r[m + 1], mw1[(m + 1) * 32 + k], a1);
                a2 = fmaf(w2r[m + 2], mw1[(m + 2) * 32 + k], a2);
                a3 = fmaf(w2r[m + 3], mw1[(m + 3) * 32 + k], a3);
            }
            wsf[j * 32 + k] = (a0 + a1) + (a2 + a3);
        } else if (tid < 192) {
            int t = tid - 128;
            int j = t & 3, ch = t >> 2;
            const float* w2c = mw2 + j * 512 + ch * 32;
            const float* b1c = mb1 + ch * 32;
            float p = 0.f;
#pragma unroll 8
            for (int m = 0; m < 32; ++m) p = fmaf(w2c[m], b1c[m], p);
            red[t] = p;
        }
        __syncthreads();
        if (tid < 4) {
            float c = mb2[tid];
#pragma unroll
            for (int i = 0; i < 16; ++i) c += red[tid + i * 4];
            wsf[128 + tid] = c;
        }
        return;
    }

    if (bx == 7) {
        if (tid < 64) {
            int lane = tid, n = lane & 15, q = lane >> 4;
            int pc0 = ((n >> 2) << 3) | (n & 3);
#pragma unroll
            for (int mt = 0; mt < 2; ++mt) {
                int co = pc0 + mt * 4;
                uint4v u = (uint4v)0u;
                if (q == 0) {
#pragma unroll
                    for (int i = 0; i < 4; ++i)
                        u[i] = packRNE(w0[(2 * i + 1) * 32 + co], w0[2 * i * 32 + co]);
                }
                *(uint4v*)(wsu + FRAG0 + mt * 256 + lane * 4) = u;
            }
        }
        return;
    }

    if (bx <= 3) {
        const float* W = (bx == 1) ? w1 : (bx == 2) ? w2 : w3;
        int fbase = 2 + (bx - 1) * 8;
        for (int i = tid; i < 4096; i += 256) {
            int k = i >> 5, co = i & 31;
            s[k * 33 + co] = (short)f2bf(W[i]);
        }
        __syncthreads();
        if (tid < 64) {
            int lane = tid, n = lane & 15, q = lane >> 4;
            int pc0 = ((n >> 2) << 3) | (n & 3);
#pragma unroll
            for (int mt = 0; mt < 2; ++mt) {
                int co = pc0 + mt * 4;
#pragma unroll
                for (int ks = 0; ks < 4; ++ks) {
                    uint4v u;
#pragma unroll
                    for (int i2 = 0; i2 < 4; ++i2) {
                        int k0 = ks * 32 + q * 8 + 2 * i2;
                        unsigned lo = (unsigned short)s[k0 * 33 + co];
                        unsigned hi = (unsigned short)s[(k0 + 1) * 33 + co];
                        u[i2] = lo | (hi << 16);
                    }
                    *(uint4v*)(wsu + FRAG0 + (fbase + mt * 4 + ks) * 256 + lane * 4) = u;
                }
            }
        }
        return;
    }

    {
        int fbase = (bx == 4) ? 26 : (bx == 5) ? 32 : 38;
        for (int i = tid; i < 3072; i += 256) {
            int o = i >> 5, k = i & 31;
            float v = (bx == 4) ? dec_wih[o * 34 + 2 + k] : (bx == 5) ? dec_whh[i] : enc_whh[i];
            s[o * 33 + k] = (short)f2bf(v);
        }
        __syncthreads();
        if (tid < 64) {
            int lane = tid, n = lane & 15, q = lane >> 4;
            int pc0 = ((n >> 2) << 3) | (n & 3);
#pragma unroll
            for (int g = 0; g < 3; ++g) {
#pragma unroll
                for (int mt = 0; mt < 2; ++mt) {
                    int row = g * 32 + pc0 + mt * 4;
                    uint4v u;
#pragma unroll
                    for (int i2 = 0; i2 < 4; ++i2) {
                        int k0 = q * 8 + 2 * i2;
                        unsigned lo = (unsigned short)s[row * 33 + k0];
                        unsigned hi = (unsigned short)s[row * 33 + k0 + 1];
                        u[i2] = lo | (hi << 16);
                    }
                    *(uint4v*)(wsu + FRAG0 + (fbase + g * 2 + mt) * 256 + lane * 4) = u;
                }
            }
        }
        return;
    }
}

// ===================== main kernel: R8 structure + swizzle-free GRU tails =====================
__global__ __launch_bounds__(256)
void r2p2_main(
    const float* __restrict__ z, const float* __restrict__ past, const float* __restrict__ lidar,
    const float* __restrict__ b0, const float* __restrict__ b1,
    const float* __restrict__ b2, const float* __restrict__ b3,
    const float* __restrict__ enc_wih, const float* __restrict__ enc_bih, const float* __restrict__ enc_bhh,
    const float* __restrict__ dec_wih, const float* __restrict__ dec_bih, const float* __restrict__ dec_bhh,
    const float* __restrict__ wsf, const unsigned* __restrict__ wsu,
    float* __restrict__ out) {

    const int tid = threadIdx.x, b = blockIdx.x;
    const int wid = tid >> 6, lane = tid & 63;
    const int n = lane & 15, q = lane >> 4;

    __shared__ __align__(16) unsigned sLID[104 * 104];
    __shared__ __align__(16) float PASTs[40];
    __shared__ __align__(16) float ZVs[64];

    if (wid != 0) {
        int st = tid - 64;   // 0..191
        if (st < 60) ZVs[st] = z[b * 60 + st];
        for (int i = st; i < 816; i += 192) {   // zero border
            int idx = (i < 416) ? (10400 + i) : ((((i - 416) >> 2) * 104) + 100 + ((i - 416) & 3));
            sLID[idx] = 0u;
        }
        const float4* lp4 = (const float4*)(lidar + (size_t)b * 20000);
#pragma unroll 4
        for (int i = st; i < 5000; i += 192) {
            int r = (int)(((unsigned)i * 5243u) >> 18);   // i / 50
            int c2 = i - r * 50;
            float4 v = lp4[i];
            int o = r * 104 + 2 * c2;
            sLID[o]     = pack_trunc(v.y, v.x);
            sLID[o + 1] = pack_trunc(v.w, v.z);
        }
        __syncthreads();
        return;
    }

    // ====== wave 0: coalesced frag loads ======
    uint4v FR[44];
#pragma unroll
    for (int f = 0; f < 44; ++f) FR[f] = *(const uint4v*)(wsu + FRAG0 + f * 256 + lane * 4);
#define FRG(f) __builtin_bit_cast(short8, FR[f])

    f32x4 cb0[2], cb1[2], cb2[2], cb3[2], gbR[2], gbZ[2], gbNi[2], gbNh[2];
    f32x4 egR[2], egZ[2], egNh[2], egNi[2];
#pragma unroll
    for (int mt = 0; mt < 2; ++mt) {
        int o = q * 8 + mt * 4;
        cb0[mt] = ld4(b0 + o); cb1[mt] = ld4(b1 + o); cb2[mt] = ld4(b2 + o); cb3[mt] = ld4(b3 + o);
        gbR[mt]  = ld4(dec_bih + o)      + ld4(dec_bhh + o);
        gbZ[mt]  = ld4(dec_bih + 32 + o) + ld4(dec_bhh + 32 + o);
        gbNi[mt] = ld4(dec_bih + 64 + o);
        gbNh[mt] = ld4(dec_bhh + 64 + o);
        egR[mt]  = ld4(enc_bih + o)      + ld4(enc_bhh + o);
        egZ[mt]  = ld4(enc_bih + 32 + o) + ld4(enc_bhh + 32 + o);
        egNi[mt] = ld4(enc_bih + 64 + o);
        egNh[mt] = ld4(enc_bhh + 64 + o);
    }
    // per-lane x-side GRU weight rows for ALL 8 channels q*8+j (swizzle-free tails)
    float2 wxr[8], wxz[8], wxn[8], wexr[8], wexz[8], wexn[8];
#pragma unroll
    for (int j = 0; j < 8; ++j) {
        int c = q * 8 + j;
        wxr[j]  = *(const float2*)(dec_wih + c * 34);
        wxz[j]  = *(const float2*)(dec_wih + (32 + c) * 34);
        wxn[j]  = *(const float2*)(dec_wih + (64 + c) * 34);
        wexr[j] = *(const float2*)(enc_wih + c * 2);
        wexz[j] = *(const float2*)(enc_wih + (32 + c) * 2);
        wexn[j] = *(const float2*)(enc_wih + (64 + c) * 2);
    }
    short8 Am = (short8)0;
    if (n < 4) {
#pragma unroll
        for (int j = 0; j < 8; ++j) Am[j] = (short)f2bf(wsf[n * 32 + q * 8 + j]);
    }
    f32x4 mcv = {0.f, 0.f, 0.f, 0.f};
    if (q == 0) mcv = *(const f32x4*)(wsf + 128);

    if (lane < 20) *(float2*)&PASTs[2 * lane] = *(const float2*)(past + b * 40 + 2 * lane);
    float q0 = past[b * 40 + 38], q1 = past[b * 40 + 39];
    float p0 = past[b * 40 + 36], p1 = past[b * 40 + 37];
    asm volatile("s_waitcnt lgkmcnt(0)" ::: "memory");

    // ====== encoder: register GRU, 20 steps, no cross-lane exchange ======
    float hq[8] = {0.f, 0.f, 0.f, 0.f, 0.f, 0.f, 0.f, 0.f};
    short8 hfr = (short8)0;
#pragma unroll 1
    for (int t = 0; t < 20; ++t) {
        float2 xp = *(const float2*)&PASTs[2 * t];
        f32x4 gr[2], gz[2], gh[2];
        gr[0] = mfma16(FRG(38), hfr, egR[0]);  gr[1] = mfma16(FRG(39), hfr, egR[1]);
        gz[0] = mfma16(FRG(40), hfr, egZ[0]);  gz[1] = mfma16(FRG(41), hfr, egZ[1]);
        gh[0] = mfma16(FRG(42), hfr, egNh[0]); gh[1] = mfma16(FRG(43), hfr, egNh[1]);
        float hn[8];
#pragma unroll
        for (int mt = 0; mt < 2; ++mt) {
#pragma unroll
            for (int r = 0; r < 4; ++r) {
                int j = mt * 4 + r;
                float rp = gr[mt][r] + xp.x * wexr[j].x + xp.y * wexr[j].y;
                float zp = gz[mt][r] + xp.x * wexz[j].x + xp.y * wexz[j].y;
                float pi = egNi[mt][r] + xp.x * wexn[j].x + xp.y * wexn[j].y;
                float rr = sigf(rp), zz = sigf(zp);
                float tn = tanhfast(fmaf(rr, gh[mt][r], pi));
                float hv = tn + zz * (hq[j] - tn);
                hq[j] = hv; hn[j] = hv;
            }
        }
        uint4v hv4;
        hv4[0] = packRNE(hn[1], hn[0]); hv4[1] = packRNE(hn[3], hn[2]);
        hv4[2] = packRNE(hn[5], hn[4]); hv4[3] = packRNE(hn[7], hn[6]);
        hfr = __builtin_bit_cast(short8, hv4);
    }

    __syncthreads();   // join staging waves

    int py0a = n / 5, px0a = n % 5;
    int pe0b = (16 + n < 25) ? 16 + n : 24;
    int py0b = pe0b / 5, px0b = pe0b - py0b * 5;
    int ofs0a[4], ofs0b[4];
#pragma unroll
    for (int tp = 0; tp < 4; ++tp) {
        ofs0a[tp] = (py0a + (tp >> 1)) * 104 + px0a + (tp & 1);
        ofs0b[tp] = (py0b + (tp >> 1)) * 104 + px0b + (tp & 1);
    }
    int py1 = n >> 2, px1 = n & 3;
    int adr1[4], sel1m[4];
#pragma unroll
    for (int ks = 0; ks < 4; ++ks) {
        int p = (py1 + (ks >> 1)) * 5 + px1 + (ks & 1);
        adr1[ks] = (q * 16 + (p & 15)) * 4;
        sel1m[ks] = (p >= 16);
    }
    int pe2 = (n < 9) ? n : 8, py2 = pe2 / 3, px2 = pe2 - py2 * 3;
    int adr2[4];
#pragma unroll
    for (int ks = 0; ks < 4; ++ks) adr2[ks] = (q * 16 + (py2 + (ks >> 1)) * 4 + px2 + (ks & 1)) * 4;
    int pe3 = n & 3, py3 = pe3 >> 1, px3 = pe3 & 1;
    int adr3[4];
#pragma unroll
    for (int ks = 0; ks < 4; ++ks) adr3[ks] = (q * 16 + (py3 + (ks >> 1)) * 3 + px3 + (ks & 1)) * 4;
    const f32x4 zf4 = {0.f, 0.f, 0.f, 0.f};
    float la = 0.f;

#pragma unroll 1
    for (int t = 0; t < 30; ++t) {
        float2 zv = *(const float2*)&ZVs[2 * t];
        float f0 = fminf(fmaxf(floorf(q0), 0.f), 98.f);
        float f1v = fminf(fmaxf(floorf(q1), 0.f), 98.f);
        int fy = (int)f0, fx = (int)f1v;
        float ay = fminf(fmaxf(q0 - f0, 0.f), 1.f);
        float ax = fminf(fmaxf(q1 - f1v, 0.f), 1.f);
        int base = fy * 104 + fx;
        int limy = 100 - fy, limx = 100 - fx;

        // ---- conv0 ----
        short8 bfa = (short8)0, bfb = (short8)0;
        if (q == 0) {
            uint4v ua, ub;
#pragma unroll
            for (int tp = 0; tp < 4; ++tp) { ua[tp] = sLID[base + ofs0a[tp]]; ub[tp] = sLID[base + ofs0b[tp]]; }
            bfa = __builtin_bit_cast(short8, ua);
            bfb = __builtin_bit_cast(short8, ub);
        }
        f32x4 ca0 = mfma16(FRG(0), bfa, cb0[0]);
        f32x4 ca1 = mfma16(FRG(1), bfa, cb0[1]);
        f32x4 cB0 = mfma16(FRG(0), bfb, cb0[0]);
        f32x4 cB1 = mfma16(FRG(1), bfb, cb0[1]);
        unsigned Pa[4], Pb[4];
        packC(Pa, ca0, ca1, (py0a >= limy) || (px0a >= limx));
        packC(Pb, cB0, cB1, (py0b >= limy) || (px0b >= limx));

        // ---- conv1 ----
        short8 bf1[4];
#pragma unroll
        for (int ks = 0; ks < 4; ++ks) {
            uint4v bu;
#pragma unroll
            for (int u = 0; u < 4; ++u) {
                unsigned va = bperm(adr1[ks], Pa[u]);
                unsigned vb = bperm(adr1[ks], Pb[u]);
                bu[u] = sel1m[ks] ? vb : va;
            }
            bf1[ks] = __builtin_bit_cast(short8, bu);
        }
        {
            f32x4 aA = mfma16(FRG(2), bf1[0], cb1[0]); aA = mfma16(FRG(3), bf1[1], aA);
            f32x4 aB = mfma16(FRG(4), bf1[2], zf4);    aB = mfma16(FRG(5), bf1[3], aB);
            f32x4 bA = mfma16(FRG(6), bf1[0], cb1[1]); bA = mfma16(FRG(7), bf1[1], bA);
            f32x4 bB = mfma16(FRG(8), bf1[2], zf4);    bB = mfma16(FRG(9), bf1[3], bB);
            f32x4 o0 = aA + aB, o1 = bA + bB;
            packC(Pa, o0, o1, (py1 >= limy) || (px1 >= limx));
        }

        // ---- conv2 ----
        short8 bf2v[4];
#pragma unroll
        for (int ks = 0; ks < 4; ++ks) {
            uint4v bu;
#pragma unroll
            for (int u = 0; u < 4; ++u) bu[u] = bperm(adr2[ks], Pa[u]);
            bf2v[ks] = __builtin_bit_cast(short8, bu);
        }
        {
            f32x4 aA = mfma16(FRG(10), bf2v[0], cb2[0]); aA = mfma16(FRG(11), bf2v[1], aA);
            f32x4 aB = mfma16(FRG(12), bf2v[2], zf4);    aB = mfma16(FRG(13), bf2v[3], aB);
            f32x4 bA = mfma16(FRG(14), bf2v[0], cb2[1]); bA = mfma16(FRG(15), bf2v[1], bA);
            f32x4 bB = mfma16(FRG(16), bf2v[2], zf4);    bB = mfma16(FRG(17), bf2v[3], bB);
            f32x4 o0 = aA + aB, o1 = bA + bB;
            packC(Pb, o0, o1, (py2 >= limy) || (px2 >= limx));
        }

        // ---- conv3 + bilinear (single DS round: 3 parallel swizzles) ----
        short8 bf3v[4];
#pragma unroll
        for (int ks = 0; ks < 4; ++ks) {
            uint4v bu;
#pragma unroll
            for (int u = 0; u < 4; ++u) bu[u] = bperm(adr3[ks], Pb[u]);
            bf3v[ks] = __builtin_bit_cast(short8, bu);
        }
        short8 xf;
        {
            f32x4 aA = mfma16(FRG(18), bf3v[0], cb3[0]); aA = mfma16(FRG(19), bf3v[1], aA);
            f32x4 aB = mfma16(FRG(20), bf3v[2], zf4);    aB = mfma16(FRG(21), bf3v[3], aB);
            f32x4 bA = mfma16(FRG(22), bf3v[0], cb3[1]); bA = mfma16(FRG(23), bf3v[1], bA);
            f32x4 bB = mfma16(FRG(24), bf3v[2], zf4);    bB = mfma16(FRG(25), bf3v[3], bB);
            f32x4 o0 = aA + aB, o1 = bA + bB;
            float wy = (n & 2) ? ay : 1.f - ay;
            float wx = (n & 1) ? ax : 1.f - ax;
            float w = wy * wx;
            float t0[4], t1[4];
#pragma unroll
            for (int r = 0; r < 4; ++r) { t0[r] = fmaxf(o0[r], 0.f) * w; t1[r] = fmaxf(o1[r], 0.f) * w; }
#pragma unroll
            for (int r = 0; r < 4; ++r) {
                float a1s = swzXf<0x041F>(t0[r]), a2s = swzXf<0x081F>(t0[r]), a3s = swzXf<0x0C1F>(t0[r]);
                t0[r] = (t0[r] + a1s) + (a2s + a3s);
                float b1s = swzXf<0x041F>(t1[r]), b2s = swzXf<0x081F>(t1[r]), b3s = swzXf<0x0C1F>(t1[r]);
                t1[r] = (t1[r] + b1s) + (b2s + b3s);
            }
            uint4v xu;
            xu[0] = packRNE(t0[1], t0[0]); xu[1] = packRNE(t0[3], t0[2]);
            xu[2] = packRNE(t1[1], t1[0]); xu[3] = packRNE(t1[3], t1[2]);
            xf = __builtin_bit_cast(short8, xu);
        }

        // ---- decoder GRU: swizzle-free tail (all 8 channels per lane) ----
        f32x4 gr[2], gz[2], gi[2], gh[2];
        gr[0] = mfma16(FRG(26), xf, gbR[0]); gr[0] = mfma16(FRG(32), hfr, gr[0]);
        gr[1] = mfma16(FRG(27), xf, gbR[1]); gr[1] = mfma16(FRG(33), hfr, gr[1]);
        gz[0] = mfma16(FRG(28), xf, gbZ[0]); gz[0] = mfma16(FRG(34), hfr, gz[0]);
        gz[1] = mfma16(FRG(29), xf, gbZ[1]); gz[1] = mfma16(FRG(35), hfr, gz[1]);
        gi[0] = mfma16(FRG(30), xf, gbNi[0]);
        gi[1] = mfma16(FRG(31), xf, gbNi[1]);
        gh[0] = mfma16(FRG(36), hfr, gbNh[0]);
        gh[1] = mfma16(FRG(37), hfr, gbNh[1]);
        float hn[8];
#pragma unroll
        for (int mt = 0; mt < 2; ++mt) {
#pragma unroll
            for (int r = 0; r < 4; ++r) {
                int j = mt * 4 + r;
                float rp = gr[mt][r] + q0 * wxr[j].x + q1 * wxr[j].y;
                float zp = gz[mt][r] + q0 * wxz[j].x + q1 * wxz[j].y;
                float pi = gi[mt][r] + q0 * wxn[j].x + q1 * wxn[j].y;
                float rr = sigf(rp), zz = sigf(zp);
                float tn = tanhfast(fmaf(rr, gh[mt][r], pi));
                float hv = tn + zz * (hq[j] - tn);
                hq[j] = hv; hn[j] = hv;
            }
        }
        uint4v hv4;
        hv4[0] = packRNE(hn[1], hn[0]); hv4[1] = packRNE(hn[3], hn[2]);
        hv4[2] = packRNE(hn[5], hn[4]); hv4[3] = packRNE(hn[7], hn[6]);
        hfr = __builtin_bit_cast(short8, hv4);

        // ---- head + tail ----
        f32x4 ls = mfma16(Am, hfr, mcv);
        float l2 = ls[2], l3 = ls[3];
        float s0 = fmaxf(l2, 0.f) + __logf(1.f + __expf(-fabsf(l2)));
        float s1 = fmaxf(l3, 0.f) + __logf(1.f + __expf(-fabsf(l3)));
        float ny0 = 2.f * q0 - p0 + ls[0] + s0 * zv.x;
        float ny1 = 2.f * q1 - p1 + ls[1] + s1 * zv.y;
        if (lane == 0) {
            float2 o2 = {ny0, ny1};
            *(float2*)(out + b * 60 + 2 * t) = o2;
        }
        la += __logf(s0 * s1);
        p0 = q0; p1 = q1;
        q0 = rfl(ny0); q1 = rfl(ny1);
    }
    if (lane == 0) out[15360 + b] = la;
#undef FRG
}

extern "C" void kernel_launch(void* const* d_in, const int* in_sizes, int n_in,
                              void* d_out, int out_size, void* d_ws, size_t ws_size,
                              hipStream_t stream) {
    const float* z    = (const float*)d_in[0];
    const float* past = (const float*)d_in[1];
    const float* lid  = (const float*)d_in[2];
    const float* c0w = (const float*)d_in[3];  const float* c0b = (const float*)d_in[4];
    const float* c1w = (const float*)d_in[5];  const float* c1b = (const float*)d_in[6];
    const float* c2w = (const float*)d_in[7];  const float* c2b = (const float*)d_in[8];
    const float* c3w = (const float*)d_in[9];  const float* c3b = (const float*)d_in[10];
    const float* ewih = (const float*)d_in[11]; const float* ewhh = (const float*)d_in[12];
    const float* ebih = (const float*)d_in[13]; const float* ebhh = (const float*)d_in[14];
    const float* dwih = (const float*)d_in[15]; const float* dwhh = (const float*)d_in[16];
    const float* dbih = (const float*)d_in[17]; const float* dbhh = (const float*)d_in[18];
    const float* mw1 = (const float*)d_in[19]; const float* mb1 = (const float*)d_in[20];
    const float* mw2 = (const float*)d_in[21]; const float* mb2 = (const float*)d_in[22];
    float* out = (float*)d_out;
    float* wsf = (float*)d_ws;
    unsigned* wsu = (unsigned*)d_ws;

    r2p2_prep<<<8, 256, 0, stream>>>(c0w, c1w, c2w, c3w, ewhh, dwih, dwhh,
                                     mw1, mb1, mw2, mb2, wsf, wsu);
    r2p2_main<<<256, 256, 0, stream>>>(z, past, lid, c0b, c1b, c2b, c3b,
                                       ewih, ebih, ebhh, dwih, dbih, dbhh,
                                       wsf, wsu, out);
}

// Round 13
// 181.717 us; speedup vs baseline: 1.1028x; 1.1028x over previous
//
#include <hip/hip_runtime.h>
#include <math.h>

typedef __attribute__((ext_vector_type(8))) short    short8;
typedef __attribute__((ext_vector_type(4))) float    f32x4;
typedef __attribute__((ext_vector_type(4))) unsigned uint4v;

#define FRAG0 256   // u32 offset of frag region in ws

__device__ __forceinline__ unsigned short f2bf(float f) {   // RNE
    unsigned u = __builtin_bit_cast(unsigned, f);
    u = u + 0x7fffu + ((u >> 16) & 1u);
    return (unsigned short)(u >> 16);
}
__device__ __forceinline__ unsigned packRNE(float hi, float lo) {
    return (unsigned)f2bf(lo) | ((unsigned)f2bf(hi) << 16);
}
__device__ __forceinline__ unsigned pack_trunc(float hi, float lo) {  // 1 v_perm
    return __builtin_amdgcn_perm(__builtin_bit_cast(unsigned, hi),
                                 __builtin_bit_cast(unsigned, lo), 0x07060302u);
}
__device__ __forceinline__ float rfl(float x) {
    return __builtin_bit_cast(float, __builtin_amdgcn_readfirstlane(__builtin_bit_cast(int, x)));
}
__device__ __forceinline__ f32x4 mfma16(short8 a, short8 b, f32x4 c) {
    return __builtin_amdgcn_mfma_f32_16x16x32_bf16(a, b, c, 0, 0, 0);
}
__device__ __forceinline__ unsigned bperm(int addr, unsigned v) {
    return (unsigned)__builtin_amdgcn_ds_bpermute(addr, (int)v);
}
template<int PAT>
__device__ __forceinline__ float swzXf(float v) {
    return __builtin_bit_cast(float, __builtin_amdgcn_ds_swizzle(__builtin_bit_cast(int, v), PAT));
}
__device__ __forceinline__ unsigned swz1u(unsigned v){ return (unsigned)__builtin_amdgcn_ds_swizzle((int)v, 0x041F); }
__device__ __forceinline__ float sigf(float x) { return __builtin_amdgcn_rcpf(1.f + __expf(-x)); }
__device__ __forceinline__ float tanhfast(float x) {
    float e = __expf(2.f * x);
    return 1.f - 2.f * __builtin_amdgcn_rcpf(e + 1.f);
}
__device__ __forceinline__ f32x4 ld4(const float* p) { return *(const f32x4*)p; }

__device__ __forceinline__ void packC(unsigned* P, f32x4 a0, f32x4 a1, bool oob) {
    float r0 = fmaxf(a0[0], 0.f), r1 = fmaxf(a0[1], 0.f), r2 = fmaxf(a0[2], 0.f), r3 = fmaxf(a0[3], 0.f);
    float s0 = fmaxf(a1[0], 0.f), s1 = fmaxf(a1[1], 0.f), s2 = fmaxf(a1[2], 0.f), s3 = fmaxf(a1[3], 0.f);
    P[0] = pack_trunc(r1, r0); P[1] = pack_trunc(r3, r2);
    P[2] = pack_trunc(s1, s0); P[3] = pack_trunc(s3, s2);
    if (oob) { P[0] = 0u; P[1] = 0u; P[2] = 0u; P[3] = 0u; }
}

// ===================== prep kernel: MLP compose + frag prepack =====================
__global__ __launch_bounds__(256) void r2p2_prep(
    const float* __restrict__ w0, const float* __restrict__ w1,
    const float* __restrict__ w2, const float* __restrict__ w3,
    const float* __restrict__ enc_whh,
    const float* __restrict__ dec_wih, const float* __restrict__ dec_whh,
    const float* __restrict__ mw1, const float* __restrict__ mb1,
    const float* __restrict__ mw2, const float* __restrict__ mb2,
    float* __restrict__ wsf, unsigned* __restrict__ wsu) {
    const int tid = threadIdx.x, bx = blockIdx.x;
    if (bx == 0) {
        // ---- composed MLP, coalesced: threads 0..127 -> M[j][k]; 128..191 -> c partials ----
        __shared__ float red[64];
        if (tid < 128) {
            int k = tid & 31, j = tid >> 5;
            const float* w2r = mw2 + j * 512;
            float a0 = 0.f, a1 = 0.f, a2 = 0.f, a3 = 0.f;
#pragma unroll 4
            for (int m = 0; m < 512; m += 4) {
                a0 = fmaf(w2r[m],     mw1[m * 32 + k],       a0);
                a1 = fmaf(w2r[m + 1], mw1[(m + 1) * 32 + k], a1);
                a2 = fmaf(w2r[m + 2], mw1[(m + 2) * 32 + k], a2);
                a3 = fmaf(w2r[m + 3], mw1[(m + 3) * 32 + k], a3);
            }
            wsf[j * 32 + k] = (a0 + a1) + (a2 + a3);
        } else if (tid < 192) {
            int t = tid - 128;          // 0..63: j = t&3, chunk = t>>2 (16 chunks of 32)
            int j = t & 3, ch = t >> 2;
            const float* w2c = mw2 + j * 512 + ch * 32;
            const float* b1c = mb1 + ch * 32;
            float p = 0.f;
#pragma unroll 8
            for (int m = 0; m < 32; ++m) p = fmaf(w2c[m], b1c[m], p);
            red[t] = p;
        }
        __syncthreads();
        if (tid < 4) {
            float c = mb2[tid];
#pragma unroll
            for (int i = 0; i < 16; ++i) c += red[tid + i * 4];
            wsf[128 + tid] = c;
        }
        return;
    }
    // ---- frag prepack: 44 frags x 64 lanes, cells split over blocks 1..7 ----
    int base = (bx - 1) * 416;
    for (int c = base + tid; c < base + 416 && c < 2816; c += 256) {
        int f = c >> 6, lane = c & 63;
        int n = lane & 15, q = lane >> 4;
        int pc0 = ((n >> 2) << 3) | (n & 3);
        float v[8];
        if (f < 2) {
            int co = pc0 + f * 4;
#pragma unroll
            for (int j = 0; j < 8; ++j) v[j] = (q == 0) ? w0[j * 32 + co] : 0.f;
        } else if (f < 26) {
            int t = f - 2;
            const float* W = (t < 8) ? w1 : (t < 16) ? w2 : w3;
            t &= 7;
            int mt = t >> 2, ks = t & 3, co = pc0 + mt * 4;
#pragma unroll
            for (int j = 0; j < 8; ++j) v[j] = W[(ks * 32 + q * 8 + j) * 32 + co];
        } else if (f < 32) {
            int t = f - 26, gate = t >> 1, mt = t & 1;
            int row = gate * 32 + pc0 + mt * 4;
#pragma unroll
            for (int j = 0; j < 8; ++j) v[j] = dec_wih[row * 34 + 2 + q * 8 + j];
        } else if (f < 38) {
            int t = f - 32, gate = t >> 1, mt = t & 1;
            int row = gate * 32 + pc0 + mt * 4;
#pragma unroll
            for (int j = 0; j < 8; ++j) v[j] = dec_whh[row * 32 + q * 8 + j];
        } else {
            int t = f - 38, gate = t >> 1, mt = t & 1;
            int row = gate * 32 + pc0 + mt * 4;
#pragma unroll
            for (int j = 0; j < 8; ++j) v[j] = enc_whh[row * 32 + q * 8 + j];
        }
        uint4v u;
        u[0] = packRNE(v[1], v[0]); u[1] = packRNE(v[3], v[2]);
        u[2] = packRNE(v[5], v[4]); u[3] = packRNE(v[7], v[6]);
        *(uint4v*)(wsu + FRAG0 + f * 256 + lane * 4) = u;
    }
}

// ===================== main kernel =====================
__global__ __launch_bounds__(256)
void r2p2_main(
    const float* __restrict__ z, const float* __restrict__ past, const float* __restrict__ lidar,
    const float* __restrict__ b0, const float* __restrict__ b1,
    const float* __restrict__ b2, const float* __restrict__ b3,
    const float* __restrict__ enc_wih, const float* __restrict__ enc_bih, const float* __restrict__ enc_bhh,
    const float* __restrict__ dec_wih, const float* __restrict__ dec_bih, const float* __restrict__ dec_bhh,
    const float* __restrict__ wsf, const unsigned* __restrict__ wsu,
    float* __restrict__ out) {

    const int tid = threadIdx.x, b = blockIdx.x;
    const int wid = tid >> 6, lane = tid & 63;
    const int n = lane & 15, q = lane >> 4, e = n & 1;

    __shared__ __align__(16) unsigned sLID[104 * 104];
    __shared__ __align__(16) float PASTs[40];
    __shared__ __align__(16) float ZVs[64];

    if (wid != 0) {
        // ====== waves 1-3: lidar staging + z ======
        int st = tid - 64;   // 0..191
        if (st < 60) ZVs[st] = z[b * 60 + st];
        for (int i = st; i < 816; i += 192) {   // zero border
            int idx = (i < 416) ? (10400 + i) : ((((i - 416) >> 2) * 104) + 100 + ((i - 416) & 3));
            sLID[idx] = 0u;
        }
        const float4* lp4 = (const float4*)(lidar + (size_t)b * 20000);
#pragma unroll 4
        for (int i = st; i < 5000; i += 192) {
            int r = (int)(((unsigned)i * 5243u) >> 18);   // i / 50
            int c2 = i - r * 50;
            float4 v = lp4[i];
            int o = r * 104 + 2 * c2;
            sLID[o]     = pack_trunc(v.y, v.x);
            sLID[o + 1] = pack_trunc(v.w, v.z);
        }
        __syncthreads();
        return;
    }

    // ====== wave 0: coalesced frag loads ======
    uint4v FR[44];
#pragma unroll
    for (int f = 0; f < 44; ++f) FR[f] = *(const uint4v*)(wsu + FRAG0 + f * 256 + lane * 4);
#define FRG(f) __builtin_bit_cast(short8, FR[f])

    f32x4 cb0[2], cb1[2], cb2[2], cb3[2], gbR[2], gbZ[2], gbNi[2], gbNh[2];
    f32x4 egR[2], egZ[2], egNh[2];
#pragma unroll
    for (int mt = 0; mt < 2; ++mt) {
        int o = q * 8 + mt * 4;
        cb0[mt] = ld4(b0 + o); cb1[mt] = ld4(b1 + o); cb2[mt] = ld4(b2 + o); cb3[mt] = ld4(b3 + o);
        gbR[mt]  = ld4(dec_bih + o)      + ld4(dec_bhh + o);
        gbZ[mt]  = ld4(dec_bih + 32 + o) + ld4(dec_bhh + 32 + o);
        gbNi[mt] = ld4(dec_bih + 64 + o);
        gbNh[mt] = ld4(dec_bhh + 64 + o);
        egR[mt]  = ld4(enc_bih + o)      + ld4(enc_bhh + o);
        egZ[mt]  = ld4(enc_bih + 32 + o) + ld4(enc_bhh + 32 + o);
        egNh[mt] = ld4(enc_bhh + 64 + o);
    }
    f32x4 ebni = ld4(enc_bih + 64 + q * 8 + e * 4);
    float2 wxr[4], wxz[4], wxn[4], wexr[4], wexz[4], wexn[4];
#pragma unroll
    for (int r = 0; r < 4; ++r) {
        int c = q * 8 + e * 4 + r;
        wxr[r]  = *(const float2*)(dec_wih + c * 34);
        wxz[r]  = *(const float2*)(dec_wih + (32 + c) * 34);
        wxn[r]  = *(const float2*)(dec_wih + (64 + c) * 34);
        wexr[r] = *(const float2*)(enc_wih + c * 2);
        wexz[r] = *(const float2*)(enc_wih + (32 + c) * 2);
        wexn[r] = *(const float2*)(enc_wih + (64 + c) * 2);
    }
    short8 Am = (short8)0;
    if (n < 4) {
#pragma unroll
        for (int j = 0; j < 8; ++j) Am[j] = (short)f2bf(wsf[n * 32 + q * 8 + j]);
    }
    f32x4 mcv = {0.f, 0.f, 0.f, 0.f};
    if (q == 0) mcv = *(const f32x4*)(wsf + 128);

    if (lane < 20) *(float2*)&PASTs[2 * lane] = *(const float2*)(past + b * 40 + 2 * lane);
    float q0 = past[b * 40 + 38], q1 = past[b * 40 + 39];
    float p0 = past[b * 40 + 36], p1 = past[b * 40 + 37];
    asm volatile("s_waitcnt lgkmcnt(0)" ::: "memory");

    // ====== encoder: register GRU, 20 steps ======
    float hq[4] = {0.f, 0.f, 0.f, 0.f};
    short8 hfr = (short8)0;
#pragma unroll 1
    for (int t = 0; t < 20; ++t) {
        float2 xp = *(const float2*)&PASTs[2 * t];
        f32x4 gr0 = mfma16(FRG(38), hfr, egR[0]),  gr1 = mfma16(FRG(39), hfr, egR[1]);
        f32x4 gz0 = mfma16(FRG(40), hfr, egZ[0]),  gz1 = mfma16(FRG(41), hfr, egZ[1]);
        f32x4 gh0 = mfma16(FRG(42), hfr, egNh[0]), gh1 = mfma16(FRG(43), hfr, egNh[1]);
        f32x4 grS = e ? gr1 : gr0, gzS = e ? gz1 : gz0, ghS = e ? gh1 : gh0;
        float hn[4];
#pragma unroll
        for (int r = 0; r < 4; ++r) {
            float rp = grS[r] + xp.x * wexr[r].x + xp.y * wexr[r].y;
            float zp = gzS[r] + xp.x * wexz[r].x + xp.y * wexz[r].y;
            float pi = ebni[r] + xp.x * wexn[r].x + xp.y * wexn[r].y;
            float rr = sigf(rp), zz = sigf(zp);
            float tn = tanhfast(fmaf(rr, ghS[r], pi));
            float hv = tn + zz * (hq[r] - tn);
            hq[r] = hv; hn[r] = hv;
        }
        unsigned hu0 = packRNE(hn[1], hn[0]), hu1 = packRNE(hn[3], hn[2]);
        unsigned po0 = swz1u(hu0), po1 = swz1u(hu1);
        uint4v hv4;
        hv4[0] = e ? po0 : hu0; hv4[1] = e ? po1 : hu1;
        hv4[2] = e ? hu0 : po0; hv4[3] = e ? hu1 : po1;
        hfr = __builtin_bit_cast(short8, hv4);
    }

    __syncthreads();   // join staging waves

    int py0a = n / 5, px0a = n % 5;
    int pe0b = (16 + n < 25) ? 16 + n : 24;
    int py0b = pe0b / 5, px0b = pe0b - py0b * 5;
    int ofs0a[4], ofs0b[4];
#pragma unroll
    for (int tp = 0; tp < 4; ++tp) {
        ofs0a[tp] = (py0a + (tp >> 1)) * 104 + px0a + (tp & 1);
        ofs0b[tp] = (py0b + (tp >> 1)) * 104 + px0b + (tp & 1);
    }
    int py1 = n >> 2, px1 = n & 3;
    int adr1[4], sel1m[4];
#pragma unroll
    for (int ks = 0; ks < 4; ++ks) {
        int p = (py1 + (ks >> 1)) * 5 + px1 + (ks & 1);
        adr1[ks] = (q * 16 + (p & 15)) * 4;
        sel1m[ks] = (p >= 16);
    }
    int pe2 = (n < 9) ? n : 8, py2 = pe2 / 3, px2 = pe2 - py2 * 3;
    int adr2[4];
#pragma unroll
    for (int ks = 0; ks < 4; ++ks) adr2[ks] = (q * 16 + (py2 + (ks >> 1)) * 4 + px2 + (ks & 1)) * 4;
    int pe3 = n & 3, py3 = pe3 >> 1, px3 = pe3 & 1;
    int adr3[4];
#pragma unroll
    for (int ks = 0; ks < 4; ++ks) adr3[ks] = (q * 16 + (py3 + (ks >> 1)) * 3 + px3 + (ks & 1)) * 4;
    const f32x4 zf4 = {0.f, 0.f, 0.f, 0.f};
    float la = 0.f;

#pragma unroll 1
    for (int t = 0; t < 30; ++t) {
        float2 zv = *(const float2*)&ZVs[2 * t];
        float f0 = fminf(fmaxf(floorf(q0), 0.f), 98.f);
        float f1v = fminf(fmaxf(floorf(q1), 0.f), 98.f);
        int fy = (int)f0, fx = (int)f1v;
        float ay = fminf(fmaxf(q0 - f0, 0.f), 1.f);
        float ax = fminf(fmaxf(q1 - f1v, 0.f), 1.f);
        int base = fy * 104 + fx;
        int limy = 100 - fy, limx = 100 - fx;

        // ---- conv0 ----
        short8 bfa = (short8)0, bfb = (short8)0;
        if (q == 0) {
            uint4v ua, ub;
#pragma unroll
            for (int tp = 0; tp < 4; ++tp) { ua[tp] = sLID[base + ofs0a[tp]]; ub[tp] = sLID[base + ofs0b[tp]]; }
            bfa = __builtin_bit_cast(short8, ua);
            bfb = __builtin_bit_cast(short8, ub);
        }
        f32x4 ca0 = mfma16(FRG(0), bfa, cb0[0]);
        f32x4 ca1 = mfma16(FRG(1), bfa, cb0[1]);
        f32x4 cB0 = mfma16(FRG(0), bfb, cb0[0]);
        f32x4 cB1 = mfma16(FRG(1), bfb, cb0[1]);
        unsigned Pa[4], Pb[4];
        packC(Pa, ca0, ca1, (py0a >= limy) || (px0a >= limx));
        packC(Pb, cB0, cB1, (py0b >= limy) || (px0b >= limx));

        // ---- conv1 ----
        short8 bf1[4];
#pragma unroll
        for (int ks = 0; ks < 4; ++ks) {
            uint4v bu;
#pragma unroll
            for (int u = 0; u < 4; ++u) {
                unsigned va = bperm(adr1[ks], Pa[u]);
                unsigned vb = bperm(adr1[ks], Pb[u]);
                bu[u] = sel1m[ks] ? vb : va;
            }
            bf1[ks] = __builtin_bit_cast(short8, bu);
        }
        {
            f32x4 aA = mfma16(FRG(2), bf1[0], cb1[0]); aA = mfma16(FRG(3), bf1[1], aA);
            f32x4 aB = mfma16(FRG(4), bf1[2], zf4);    aB = mfma16(FRG(5), bf1[3], aB);
            f32x4 bA = mfma16(FRG(6), bf1[0], cb1[1]); bA = mfma16(FRG(7), bf1[1], bA);
            f32x4 bB = mfma16(FRG(8), bf1[2], zf4);    bB = mfma16(FRG(9), bf1[3], bB);
            f32x4 o0 = aA + aB, o1 = bA + bB;
            packC(Pa, o0, o1, (py1 >= limy) || (px1 >= limx));
        }

        // ---- conv2 ----
        short8 bf2v[4];
#pragma unroll
        for (int ks = 0; ks < 4; ++ks) {
            uint4v bu;
#pragma unroll
            for (int u = 0; u < 4; ++u) bu[u] = bperm(adr2[ks], Pa[u]);
            bf2v[ks] = __builtin_bit_cast(short8, bu);
        }
        {
            f32x4 aA = mfma16(FRG(10), bf2v[0], cb2[0]); aA = mfma16(FRG(11), bf2v[1], aA);
            f32x4 aB = mfma16(FRG(12), bf2v[2], zf4);    aB = mfma16(FRG(13), bf2v[3], aB);
            f32x4 bA = mfma16(FRG(14), bf2v[0], cb2[1]); bA = mfma16(FRG(15), bf2v[1], bA);
            f32x4 bB = mfma16(FRG(16), bf2v[2], zf4);    bB = mfma16(FRG(17), bf2v[3], bB);
            f32x4 o0 = aA + aB, o1 = bA + bB;
            packC(Pb, o0, o1, (py2 >= limy) || (px2 >= limx));
        }

        // ---- conv3 + bilinear (single DS round: 3 parallel swizzles) ----
        short8 bf3v[4];
#pragma unroll
        for (int ks = 0; ks < 4; ++ks) {
            uint4v bu;
#pragma unroll
            for (int u = 0; u < 4; ++u) bu[u] = bperm(adr3[ks], Pb[u]);
            bf3v[ks] = __builtin_bit_cast(short8, bu);
        }
        short8 xf;
        {
            f32x4 aA = mfma16(FRG(18), bf3v[0], cb3[0]); aA = mfma16(FRG(19), bf3v[1], aA);
            f32x4 aB = mfma16(FRG(20), bf3v[2], zf4);    aB = mfma16(FRG(21), bf3v[3], aB);
            f32x4 bA = mfma16(FRG(22), bf3v[0], cb3[1]); bA = mfma16(FRG(23), bf3v[1], bA);
            f32x4 bB = mfma16(FRG(24), bf3v[2], zf4);    bB = mfma16(FRG(25), bf3v[3], bB);
            f32x4 o0 = aA + aB, o1 = bA + bB;
            float wy = (n & 2) ? ay : 1.f - ay;
            float wx = (n & 1) ? ax : 1.f - ax;
            float w = wy * wx;
            float t0[4], t1[4];
#pragma unroll
            for (int r = 0; r < 4; ++r) { t0[r] = fmaxf(o0[r], 0.f) * w; t1[r] = fmaxf(o1[r], 0.f) * w; }
#pragma unroll
            for (int r = 0; r < 4; ++r) {
                float a1 = swzXf<0x041F>(t0[r]), a2 = swzXf<0x081F>(t0[r]), a3 = swzXf<0x0C1F>(t0[r]);
                t0[r] = (t0[r] + a1) + (a2 + a3);
                float b1v = swzXf<0x041F>(t1[r]), b2v = swzXf<0x081F>(t1[r]), b3v = swzXf<0x0C1F>(t1[r]);
                t1[r] = (t1[r] + b1v) + (b2v + b3v);
            }
            uint4v xu;
            xu[0] = packRNE(t0[1], t0[0]); xu[1] = packRNE(t0[3], t0[2]);
            xu[2] = packRNE(t1[1], t1[0]); xu[3] = packRNE(t1[3], t1[2]);
            xf = __builtin_bit_cast(short8, xu);
        }

        // ---- decoder GRU ----
        f32x4 gr0 = mfma16(FRG(26), xf, gbR[0]); gr0 = mfma16(FRG(32), hfr, gr0);
        f32x4 gr1 = mfma16(FRG(27), xf, gbR[1]); gr1 = mfma16(FRG(33), hfr, gr1);
        f32x4 gz0 = mfma16(FRG(28), xf, gbZ[0]); gz0 = mfma16(FRG(34), hfr, gz0);
        f32x4 gz1 = mfma16(FRG(29), xf, gbZ[1]); gz1 = mfma16(FRG(35), hfr, gz1);
        f32x4 gi0 = mfma16(FRG(30), xf, gbNi[0]);
        f32x4 gi1 = mfma16(FRG(31), xf, gbNi[1]);
        f32x4 gh0 = mfma16(FRG(36), hfr, gbNh[0]);
        f32x4 gh1 = mfma16(FRG(37), hfr, gbNh[1]);
        f32x4 grS = e ? gr1 : gr0, gzS = e ? gz1 : gz0, giS = e ? gi1 : gi0, ghS = e ? gh1 : gh0;
        float hn[4];
#pragma unroll
        for (int r = 0; r < 4; ++r) {
            float rp = grS[r] + q0 * wxr[r].x + q1 * wxr[r].y;
            float zp = gzS[r] + q0 * wxz[r].x + q1 * wxz[r].y;
            float pi = giS[r] + q0 * wxn[r].x + q1 * wxn[r].y;
            float rr = sigf(rp), zz = sigf(zp);
            float tn = tanhfast(fmaf(rr, ghS[r], pi));
            float hv = tn + zz * (hq[r] - tn);
            hq[r] = hv; hn[r] = hv;
        }
        unsigned hu0 = packRNE(hn[1], hn[0]), hu1 = packRNE(hn[3], hn[2]);
        unsigned po0 = swz1u(hu0), po1 = swz1u(hu1);
        uint4v hv4;
        hv4[0] = e ? po0 : hu0; hv4[1] = e ? po1 : hu1;
        hv4[2] = e ? hu0 : po0; hv4[3] = e ? hu1 : po1;
        hfr = __builtin_bit_cast(short8, hv4);

        // ---- head + tail ----
        f32x4 ls = mfma16(Am, hfr, mcv);
        float l2 = ls[2], l3 = ls[3];
        float s0 = fmaxf(l2, 0.f) + __logf(1.f + __expf(-fabsf(l2)));
        float s1 = fmaxf(l3, 0.f) + __logf(1.f + __expf(-fabsf(l3)));
        float ny0 = 2.f * q0 - p0 + ls[0] + s0 * zv.x;
        float ny1 = 2.f * q1 - p1 + ls[1] + s1 * zv.y;
        if (lane == 0) {
            float2 o2 = {ny0, ny1};
            *(float2*)(out + b * 60 + 2 * t) = o2;
        }
        la += __logf(s0 * s1);
        p0 = q0; p1 = q1;
        q0 = rfl(ny0); q1 = rfl(ny1);
    }
    if (lane == 0) out[15360 + b] = la;
#undef FRG
}

extern "C" void kernel_launch(void* const* d_in, const int* in_sizes, int n_in,
                              void* d_out, int out_size, void* d_ws, size_t ws_size,
                              hipStream_t stream) {
    const float* z    = (const float*)d_in[0];
    const float* past = (const float*)d_in[1];
    const float* lid  = (const float*)d_in[2];
    const float* c0w = (const float*)d_in[3];  const float* c0b = (const float*)d_in[4];
    const float* c1w = (const float*)d_in[5];  const float* c1b = (const float*)d_in[6];
    const float* c2w = (const float*)d_in[7];  const float* c2b = (const float*)d_in[8];
    const float* c3w = (const float*)d_in[9];  const float* c3b = (const float*)d_in[10];
    const float* ewih = (const float*)d_in[11]; const float* ewhh = (const float*)d_in[12];
    const float* ebih = (const float*)d_in[13]; const float* ebhh = (const float*)d_in[14];
    const float* dwih = (const float*)d_in[15]; const float* dwhh = (const float*)d_in[16];
    const float* dbih = (const float*)d_in[17]; const float* dbhh = (const float*)d_in[18];
    const float* mw1 = (const float*)d_in[19]; const float* mb1 = (const float*)d_in[20];
    const float* mw2 = (const float*)d_in[21]; const float* mb2 = (const float*)d_in[22];
    float* out = (float*)d_out;
    float* wsf = (float*)d_ws;
    unsigned* wsu = (unsigned*)d_ws;

    r2p2_prep<<<8, 256, 0, stream>>>(c0w, c1w, c2w, c3w, ewhh, dwih, dwhh,
                                     mw1, mb1, mw2, mb2, wsf, wsu);
    r2p2_main<<<256, 256, 0, stream>>>(z, past, lid, c0b, c1b, c2b, c3b,
                                       ewih, ebih, ebhh, dwih, dbih, dbhh,
                                       wsf, wsu, out);
}